// Round 7
// baseline (516.200 us; speedup 1.0000x reference)
//
#include <hip/hip_runtime.h>

#define NSTEP 100
#define LP 10  // ring positions per lane; 4 lanes (one quad) per 40-dim ring

// Packed pair: component .x = row0, .y = row1 of a row-pair.
typedef float v2 __attribute__((ext_vector_type(2)));

__device__ __forceinline__ v2 sp(float s) { v2 r = {s, s}; return r; }
__device__ __forceinline__ v2 vfma(v2 a, v2 b, v2 c) { return __builtin_elementwise_fma(a, b, c); }

// DPP quad_perm ring rotation, componentwise (DPP is 32-bit).
__device__ __forceinline__ float dppf_prev(float v) {  // from lane (sub-1)&3
    return __int_as_float(__builtin_amdgcn_mov_dpp(__float_as_int(v), 0x93, 0xf, 0xf, true));
}
__device__ __forceinline__ float dppf_next(float v) {  // from lane (sub+1)&3
    return __int_as_float(__builtin_amdgcn_mov_dpp(__float_as_int(v), 0x39, 0xf, 0xf, true));
}
__device__ __forceinline__ v2 dpp_prev(v2 v) { v2 r; r.x = dppf_prev(v.x); r.y = dppf_prev(v.y); return r; }
__device__ __forceinline__ v2 dpp_next(v2 v) { v2 r; r.x = dppf_next(v.x); r.y = dppf_next(v.y); return r; }

// Out-of-place ONLY: k = f(a). No rolling-window renames — on v2 (even-aligned
// VGPR pairs) the in-place window forced real v_mov pairs (round 6 measured
// 5.46 cyc/instr vs the 4.0 scalar baseline of rounds 2-5; suspected rename
// movs on pair-constrained registers). Pure 4-read/1-write dataflow instead.
__device__ __forceinline__ void l96_seg(const v2* __restrict__ a, v2* __restrict__ k) {
    const v2 hm2 = dpp_prev(a[LP - 2]);  // a[m-2] for j=0
    const v2 hm1 = dpp_prev(a[LP - 1]);  // a[m-1] for j=0
    const v2 hp1 = dpp_next(a[0]);       // a[m+1] for j=LP-1
    const v2 F = sp(8.0f);
    k[0] = vfma(a[1] - hm2, hm1, F - a[0]);
    k[1] = vfma(a[2] - hm1, a[0], F - a[1]);
#pragma unroll
    for (int j = 2; j < LP - 1; ++j)
        k[j] = vfma(a[j + 1] - a[j - 2], a[j - 1], F - a[j]);
    k[LP - 1] = vfma(hp1 - a[LP - 3], a[LP - 2], F - a[LP - 1]);
}

// Round-2 RK4(3/8) flow (bit-identical fmaf sequence per element), 2 rows
// packed per thread (VOP3P), 4 lanes per row-pair, all evals out-of-place
// via a 5th scratch array. Live peak: 5 arrays x 10 v2 = 100 VGPRs + temps.
__global__ void __launch_bounds__(256)
lorenz96_rk4_kernel(const float* __restrict__ in,
                    float* __restrict__ out,
                    int batch) {
    const int gtid = blockIdx.x * blockDim.x + threadIdx.x;
    const int rp  = gtid >> 2;   // row-pair index
    const int sub = gtid & 3;    // quad lane: ring positions [sub*10, sub*10+10)
    if (rp >= (batch >> 1)) return;

    const float* __restrict__ r0 = in + (size_t)(2 * rp) * 40 + sub * LP;
    const float* __restrict__ r1 = r0 + 40;

    v2 X[LP];  // x  -> b  -> a4 -> x'
    v2 W[LP];  // k1 -> u  -> a3 -> k4
    v2 A[LP];  // acc
    v2 S[LP];  // a2 -> k3
    v2 T[LP];  // k2 (scratch dest)
#pragma unroll
    for (int j = 0; j < LP; ++j) { X[j].x = r0[j]; X[j].y = r1[j]; }

    const float dt  = 0.01f;
    const float dt3 = dt * (1.0f / 3.0f);  // dt/3
    const float dt8 = dt * 0.125f;         // dt/8
    const v2 vdt3 = sp(dt3), vdt = sp(dt), vndt = sp(-dt);
    const v2 vdt8 = sp(dt8), vth = sp(3.0f * dt8), v3 = sp(3.0f), v0375 = sp(0.375f);

#pragma unroll 1
    for (int s = 0; s < NSTEP; ++s) {
        // k1 = f(x):  X -> W
        l96_seg(X, W);

        // u = dt/3*k1 ; acc = x + 0.375*u ; a2 = x + u
#pragma unroll
        for (int i = 0; i < LP; ++i) {
            W[i] = vdt3 * W[i];
            A[i] = vfma(v0375, W[i], X[i]);
            S[i] = X[i] + W[i];
        }

        // k2 = f(a2):  S -> T
        l96_seg(S, T);

        // acc += 3dt/8*k2 ; a3 = (x-u) + dt*k2 ; b = (x+3u) - dt*k2
#pragma unroll
        for (int i = 0; i < LP; ++i) {
            A[i] = vfma(vth, T[i], A[i]);
            const v2 t = X[i] - W[i];
            X[i] = vfma(vndt, T[i], vfma(v3, W[i], X[i]));  // b
            W[i] = vfma(vdt, T[i], t);                      // a3
        }

        // k3 = f(a3):  W -> S
        l96_seg(W, S);

        // acc += 3dt/8*k3 ; a4 = b + dt*k3
#pragma unroll
        for (int i = 0; i < LP; ++i) {
            A[i] = vfma(vth, S[i], A[i]);
            X[i] = vfma(vdt, S[i], X[i]);
        }

        // k4 = f(a4):  X -> W
        l96_seg(X, W);

        // x' = acc + dt/8*k4
#pragma unroll
        for (int i = 0; i < LP; ++i) X[i] = vfma(vdt8, W[i], A[i]);
    }

    float* __restrict__ o0 = out + (size_t)(2 * rp) * 40 + sub * LP;
    float* __restrict__ o1 = o0 + 40;
#pragma unroll
    for (int j = 0; j < LP; ++j) { o0[j] = X[j].x; o1[j] = X[j].y; }
}

extern "C" void kernel_launch(void* const* d_in, const int* in_sizes, int n_in,
                              void* d_out, int out_size, void* d_ws, size_t ws_size,
                              hipStream_t stream) {
    const float* x = (const float*)d_in[0];
    float* out = (float*)d_out;
    const int batch = in_sizes[0] / 40;              // 262144 (even)
    const int block = 256;
    const long long threads = (long long)(batch / 2) * 4;  // 4 lanes per row-pair
    const int grid = (int)((threads + block - 1) / block);
    lorenz96_rk4_kernel<<<grid, block, 0, stream>>>(x, out, batch);
}